// Round 4
// baseline (403.094 us; speedup 1.0000x reference)
//
#include <hip/hip_runtime.h>
#include <hip/hip_bf16.h>

// LocalPushLoss on MI355X (gfx950).
// losses[i] = max(0, M_i - thr_i),
//   M_i  = max over j with target[j]!=target[i] of <emb_i, emb_j>
//   thr_i = max(cos_theta[i, target[i]], 0.1) - 0.1
// out = mean(losses). bf16 MFMA GEMM E*E^T (N=16384, D=256) + fused masked
// row-max. 137.4 GFLOP -> 54.6us floor (m119: 32.3 cyc/MFMA/SIMD).
//
// Structure (round 3): prep pre-permutes normalized embeddings into MFMA
// fragment order embT[tile64][ch2][kk16][lane64]*16B. Both A and B fragment
// loads are then base+lane*16 -> perfectly coalesced 1KB global transactions
// from L2 (B chunk = 1MB/XCD, L2-resident via XCD-aware block mapping).
// No LDS, no barriers, no swizzle: waves fully independent, A resident in
// 128 VGPRs (zero steady-state A traffic), 2 MFMA per B fragment load.

#define N 16384
#define D 256
#define C 1000
#define MARGIN 0.1f

#define WAVES 4
#define WR 64                    // rows per wave (2 x 32-row MFMA frags)
#define BM (WAVES * WR)          // 256 rows per block
#define BN 64                    // columns per tile step
#define COLSPLIT 8               // one column chunk per XCD
#define CCHUNK (N / COLSPLIT)    // 2048 columns per block
#define NT (CCHUNK / BN)         // 32 tiles
#define TILEB 32768              // bytes per 64-row tile in embT

typedef __attribute__((ext_vector_type(8))) short bf16x8;    // 4 VGPR
typedef __attribute__((ext_vector_type(16))) float f32x16;   // 32x32 C/D

// ---------------------------------------------------------------- prep ------
// One wave per row: L2-normalize fp32 -> bf16, scatter into embT fragment
// order. Lane l holds row bytes [l*8, l*8+8): kk=l>>2, kh=(l>>1)&1, half=l&1.
// embT piece address: tile*32768 + ch*16384 + kk*1024 + (kh*32+c)*16 + half*8
// where tile=row>>6, ch=(row&63)>>5, c=row&31.
__global__ void __launch_bounds__(256) prep_kernel(
    const float* __restrict__ features,
    char* __restrict__ embT,
    unsigned* __restrict__ rowmax_enc) {
  const int wave = threadIdx.x >> 6;
  const int lane = threadIdx.x & 63;
  const int row = blockIdx.x * 4 + wave;

  const float4 v =
      reinterpret_cast<const float4*>(features + (size_t)row * D)[lane];
  float ss = v.x * v.x + v.y * v.y + v.z * v.z + v.w * v.w;
#pragma unroll
  for (int off = 32; off >= 1; off >>= 1) ss += __shfl_xor(ss, off);
  const float inv = 1.0f / fmaxf(sqrtf(ss), 1e-12f);  // F.normalize eps

  __hip_bfloat16 e0 = __float2bfloat16(v.x * inv);
  __hip_bfloat16 e1 = __float2bfloat16(v.y * inv);
  __hip_bfloat16 e2 = __float2bfloat16(v.z * inv);
  __hip_bfloat16 e3 = __float2bfloat16(v.w * inv);
  ushort4 pack;
  pack.x = *reinterpret_cast<unsigned short*>(&e0);
  pack.y = *reinterpret_cast<unsigned short*>(&e1);
  pack.z = *reinterpret_cast<unsigned short*>(&e2);
  pack.w = *reinterpret_cast<unsigned short*>(&e3);

  const int tile = row >> 6;
  const int cit  = row & 63;
  const int ch   = cit >> 5;
  const int c    = cit & 31;
  const int kk   = lane >> 2;
  const int kh   = (lane >> 1) & 1;
  const int half = lane & 1;
  char* dst = embT + (size_t)tile * TILEB + ch * 16384 + kk * 1024 +
              (kh * 32 + c) * 16 + half * 8;
  *reinterpret_cast<ushort4*>(dst) = pack;   // 8-B aligned

  // ws re-poisoned (0xAA) before every timed launch -> re-init every call.
  // enc(-2.0f): bits 0xC0000000 (neg) -> enc = ~bits = 0x3FFFFFFF.
  if (lane == 0) rowmax_enc[row] = 0x3FFFFFFFu;
}

// -------------------------------------------------------------- pushmax -----
// 4 waves/block, wave owns 64 rows (A resident, 128 VGPR). C/D layout
// (HW-verified m74/m101): col = lane&31, row = (r&3)+8*(r>>2)+4*(lane>>5).
// A and B use the IDENTICAL (lane,reg)->(row,k) fragment map via embT, so
// any k-permutation cancels for E*E^T.
__global__ void __launch_bounds__(256, 2) pushmax_kernel(
    const char* __restrict__ embT,
    const int* __restrict__ target,
    unsigned* __restrict__ rowmax_enc) {
  const int tid  = threadIdx.x;
  const int wave = tid >> 6;
  const int lane = tid & 63;
  const int col  = lane & 31;
  const int kh   = lane >> 5;

  // XCD-aware: flat%8 == XCD (round-robin dispatch) == column chunk.
  const int flat = blockIdx.x;
  const int bx = flat >> 3;        // row panel    [0,64)
  const int by = flat & 7;         // column chunk [0,8)

  const int i0 = bx * BM + wave * WR;   // 64-aligned
  const int j0 = by * CCHUNK;

  // ---- A: 64 rows resident. a[f][kk] = embT[i0/64][f][kk][lane].
  bf16x8 a[2][16];
  {
    const char* abase = embT + (size_t)(i0 >> 6) * TILEB + lane * 16;
#pragma unroll
    for (int f = 0; f < 2; ++f)
#pragma unroll
      for (int kk = 0; kk < 16; ++kk)
        a[f][kk] = *reinterpret_cast<const bf16x8*>(abase + f * 16384 + kk * 1024);
  }

  // Row targets for the 16 C-regs per frag, packed 2/int (C=1000 < 2^16).
  int tip[2][8];
#pragma unroll
  for (int f = 0; f < 2; ++f)
#pragma unroll
    for (int p = 0; p < 8; ++p) {
      const int r0 = 2 * p, r1 = 2 * p + 1;
      const int row0 = (r0 & 3) + 8 * (r0 >> 2) + 4 * kh;
      const int row1 = (r1 & 3) + 8 * (r1 >> 2) + 4 * kh;
      tip[f][p] = (target[i0 + f * 32 + row0] & 0xffff) |
                  (target[i0 + f * 32 + row1] << 16);
    }

  float rmax[2][16];
#pragma unroll
  for (int f = 0; f < 2; ++f)
#pragma unroll
    for (int r = 0; r < 16; ++r) rmax[f][r] = -2.0f;

  for (int t = 0; t < NT; ++t) {
    const char* bbase = embT + (size_t)((j0 >> 6) + t) * TILEB + lane * 16;
    const int tjc[2] = {target[j0 + t * BN + col],
                        target[j0 + t * BN + 32 + col]};

#pragma unroll
    for (int ch = 0; ch < 2; ++ch) {
      f32x16 acc0 = {0.f, 0.f, 0.f, 0.f, 0.f, 0.f, 0.f, 0.f,
                     0.f, 0.f, 0.f, 0.f, 0.f, 0.f, 0.f, 0.f};
      f32x16 acc1 = acc0;
      // Two K-halves of 8 frags: B window = 32 VGPR, 8 loads in flight.
#pragma unroll
      for (int h = 0; h < 2; ++h) {
        bf16x8 b[8];
#pragma unroll
        for (int k8 = 0; k8 < 8; ++k8)
          b[k8] = *reinterpret_cast<const bf16x8*>(
              bbase + ch * 16384 + (h * 8 + k8) * 1024);
#pragma unroll
        for (int k8 = 0; k8 < 8; ++k8) {
          acc0 = __builtin_amdgcn_mfma_f32_32x32x16_bf16(a[0][h * 8 + k8],
                                                         b[k8], acc0, 0, 0, 0);
          acc1 = __builtin_amdgcn_mfma_f32_32x32x16_bf16(a[1][h * 8 + k8],
                                                         b[k8], acc1, 0, 0, 0);
        }
      }
      const int tj = tjc[ch];
#pragma unroll
      for (int r = 0; r < 16; ++r) {
        const int tiv0 = (tip[0][r >> 1] >> ((r & 1) << 4)) & 0xffff;
        const int tiv1 = (tip[1][r >> 1] >> ((r & 1) << 4)) & 0xffff;
        rmax[0][r] = fmaxf(rmax[0][r], (tj != tiv0) ? acc0[r] : -2.0f);
        rmax[1][r] = fmaxf(rmax[1][r], (tj != tiv1) ? acc1[r] : -2.0f);
      }
    }
  }

  // Reduce over the 32 columns each half-group holds (xor stays in-group).
#pragma unroll
  for (int off = 1; off < 32; off <<= 1)
#pragma unroll
    for (int f = 0; f < 2; ++f)
#pragma unroll
      for (int r = 0; r < 16; ++r)
        rmax[f][r] = fmaxf(rmax[f][r], __shfl_xor(rmax[f][r], off));

  if (col == 0) {  // lanes 0 (kh=0) and 32 (kh=1)
#pragma unroll
    for (int f = 0; f < 2; ++f)
#pragma unroll
      for (int r = 0; r < 16; ++r) {
        const unsigned bits = __float_as_uint(rmax[f][r]);
        const unsigned enc = bits ^ ((bits >> 31) ? 0xFFFFFFFFu : 0x80000000u);
        const int row = i0 + f * 32 + ((r & 3) + 8 * (r >> 2) + 4 * kh);
        atomicMax(&rowmax_enc[row], enc);  // device scope
      }
  }
}

// ------------------------------------------------------------- finalize -----
__global__ void __launch_bounds__(256) finalize_kernel(
    const unsigned* __restrict__ rowmax_enc,
    const float* __restrict__ cos_theta,
    const int* __restrict__ target,
    float* __restrict__ out) {
  const int i = blockIdx.x * 256 + (int)threadIdx.x;
  const unsigned enc = rowmax_enc[i];
  const unsigned bits = (enc & 0x80000000u) ? (enc ^ 0x80000000u) : ~enc;
  const float m = __uint_as_float(bits);
  const int t = target[i];
  const float thr = fmaxf(cos_theta[(size_t)i * C + t], MARGIN) - MARGIN;
  float local = fmaxf(m - thr, 0.0f) * (1.0f / (float)N);

#pragma unroll
  for (int off = 32; off >= 1; off >>= 1) local += __shfl_xor(local, off);

  __shared__ float ss[4];
  const int wid = threadIdx.x >> 6;
  if ((threadIdx.x & 63) == 0) ss[wid] = local;
  __syncthreads();
  if (threadIdx.x == 0) atomicAdd(out, ss[0] + ss[1] + ss[2] + ss[3]);
}

// --------------------------------------------------------------- launch -----
extern "C" void kernel_launch(void* const* d_in, const int* in_sizes, int n_in,
                              void* d_out, int out_size, void* d_ws, size_t ws_size,
                              hipStream_t stream) {
  const float* features  = (const float*)d_in[0];
  const float* cos_theta = (const float*)d_in[1];
  const int*   target    = (const int*)d_in[2];
  float* out = (float*)d_out;

  char* embT = (char*)d_ws;                                   // 8 MB
  unsigned* rowmax_enc = (unsigned*)((char*)d_ws + (size_t)(N / 64) * TILEB);

  prep_kernel<<<N / 4, 256, 0, stream>>>(features, embT, rowmax_enc);

  pushmax_kernel<<<(N / BM) * COLSPLIT, 256, 0, stream>>>(embT, target,
                                                          rowmax_enc);

  hipMemsetAsync(out, 0, sizeof(float), stream);
  finalize_kernel<<<N / 256, 256, 0, stream>>>(rowmax_enc, cos_theta, target,
                                               out);
}